// Round 4
// baseline (204.464 us; speedup 1.0000x reference)
//
#include <hip/hip_runtime.h>

// Barrel shift right each 64-float row by S = sum_j shift[j]*2^(5-j)
// (shift entries exactly 0/1):  out[row][k] = (k>=S) ? data[row][k-S] : 0.
//
// Key idea: realize the shift in the LOAD ADDRESS, not via shuffles.
// Lane covering output words p0..p0+3 loads 16B at float index
// row*64 + p0 - S (4B-aligned). Underflow words land in the previous
// row's tail and are masked to zero (q0+j<0). Only the global first row
// can read before the buffer -> clamp + tiny divergent fixup (first wave only).
//
// Wave layout: 4 rows/wave, 16 lanes/row, float4 per lane. Shift words are
// prefetched one iteration ahead so data-load addresses never wait on them.

typedef float f4 __attribute__((ext_vector_type(4)));

__device__ __forceinline__ f4 shifted_load(const float* __restrict__ data,
                                           int rowbase, int q0) {
    int fidx  = rowbase + q0;          // global float index of first source word
    int fidxc = fidx < 0 ? 0 : fidx;   // clamp (only first row of array)
    f4 v;
    __builtin_memcpy(&v, data + fidxc, 16);   // unaligned-ok 16B load
    f4 o;
    o.x = (q0 >= 0)  ? v.x : 0.0f;
    o.y = (q0 >= -1) ? v.y : 0.0f;
    o.z = (q0 >= -2) ? v.z : 0.0f;
    o.w = (q0 >= -3) ? v.w : 0.0f;
    if (fidx < 0) {
        // clamped load returned data[0..3]; valid elems are loaded[q0+j], q0+j in [0,2]
        int p1 = q0 + 1, p2 = q0 + 2, p3 = q0 + 3;
        float e0 = v.x, e1 = v.y, e2 = v.z;
        o.x = 0.0f;
        o.y = (p1 == 0) ? e0 : ((p1 == 1) ? e1 : ((p1 == 2) ? e2 : 0.0f));
        o.z = (p2 == 0) ? e0 : ((p2 == 1) ? e1 : ((p2 == 2) ? e2 : 0.0f));
        o.w = (p3 == 0) ? e0 : ((p3 == 1) ? e1 : ((p3 == 2) ? e2 : 0.0f));
    }
    return o;
}

__global__ __launch_bounds__(256)
void BarrelShifterRight64_kernel(const float* __restrict__ data,
                                 const float* __restrict__ shift,
                                 float* __restrict__ out,
                                 int nwrows) {
    const int lane = threadIdx.x & 63;
    const int wib  = threadIdx.x >> 6;
    const int wpb  = blockDim.x >> 6;
    const int nw   = gridDim.x * wpb;
    const int w0   = blockIdx.x * wpb + wib;

    f4* __restrict__ o4 = (f4*)out;

    const int g   = lane >> 4;
    const int t16 = lane & 15;
    const bool sl = lane < 24;

    // prologue: shift words for the first unrolled pair
    int wA = w0, wB = w0 + nw;
    float svA = (sl && wA < nwrows) ? shift[wA * 24 + lane] : 0.0f;
    float svB = (sl && wB < nwrows) ? shift[wB * 24 + lane] : 0.0f;

    for (int w = w0; w < nwrows; w += 2 * nw) {
        const int w1 = w + nw;
        const bool have1 = w1 < nwrows;

        unsigned long long bA = __ballot(svA > 0.5f);
        unsigned long long bB = __ballot(svB > 0.5f);

        // prefetch next pair's shift words (hides under the data loads below)
        const int wA2 = w + 2 * nw, wB2 = w + 3 * nw;
        svA = (sl && wA2 < nwrows) ? shift[wA2 * 24 + lane] : 0.0f;
        svB = (sl && wB2 < nwrows) ? shift[wB2 * 24 + lane] : 0.0f;

        // row-set A
        unsigned subA = (unsigned)(bA >> (6 * g)) & 63u;
        int SA  = (int)(__brev(subA) >> 26);       // MSB-first control word
        int q0A = t16 * 4 - SA;
        f4 oA = shifted_load(data, w * 256 + g * 64, q0A);

        // row-set B (independent -> loads overlap)
        f4 oB;
        if (have1) {
            unsigned subB = (unsigned)(bB >> (6 * g)) & 63u;
            int SB  = (int)(__brev(subB) >> 26);
            int q0B = t16 * 4 - SB;
            oB = shifted_load(data, w1 * 256 + g * 64, q0B);
        }

        __builtin_nontemporal_store(oA, &o4[w * 64 + lane]);
        if (have1) __builtin_nontemporal_store(oB, &o4[w1 * 64 + lane]);
    }
}

extern "C" void kernel_launch(void* const* d_in, const int* in_sizes, int n_in,
                              void* d_out, int out_size, void* d_ws, size_t ws_size,
                              hipStream_t stream) {
    const float* data  = (const float*)d_in[0];
    const float* shift = (const float*)d_in[1];
    float* out = (float*)d_out;

    const int nrows  = in_sizes[0] / 64;   // B
    const int nwrows = nrows / 4;          // 4 rows per wave

    const int block = 256;
    const int grid  = 2048;                // 8192 waves, grid-stride, unroll x2
    BarrelShifterRight64_kernel<<<grid, block, 0, stream>>>(data, shift, out, nwrows);
}